// Round 5
// baseline (137.848 us; speedup 1.0000x reference)
//
#include <hip/hip_runtime.h>

// Problem constants (from setup_inputs): B=32, S=524288, HOP=256, L=100.
constexpr int HOP    = 256;
constexpr int L      = 100;
constexpr int FRAMES = 2048;   // S / HOP
constexpr int B      = 32;
constexpr int FPB    = 8;      // frames per block: 256 thr * 8 elem = 2048 = 8*HOP
constexpr int ROWS   = FPB + 1;
constexpr int LSTR   = L + 1;  // LDS row stride in floats (odd -> full 32-bank spread,
                               // entry 100 = wrap column = row's col 0)

// One block = 8 consecutive frames of one batch row. LDS holds rows f0..f0+8
// flat (stride 101, wrap col included). Per element the 2x2 bilinear gather is
// two ds_read2_b32's: {fi, fi+1} and {fi+101, fi+102} off one base address.
//
// R4 -> R5: the block was latency-bound (41 us, no pipe >35%): staging-load
// round-trip -> barrier -> wp-load round-trip were SERIALIZED (barrier is a
// full fence; compiler can't hoist the wp load above it). Issue the wp loads
// FIRST so both global round-trips are in flight together.
// NOTE: nontemporal loads/stores REGRESSED (137.6 vs 134.7 us total) — keep
// plain float4 accesses.
__global__ __launch_bounds__(256) void glottal_kernel(
    const float* __restrict__ wp,
    const float* __restrict__ tables,
    float* __restrict__ out)
{
    __shared__ float tab[ROWS * LSTR];   // 909 floats = 3636 B

    const int tid = threadIdx.x;
    const int b   = blockIdx.x >> 8;          // / (FRAMES/FPB) = 256
    const int g   = blockIdx.x & 255;
    const int f0  = g * FPB;

    const size_t base = ((size_t)b * FRAMES + (size_t)f0) * HOP + (size_t)tid * 8;

    // Issue streaming wp loads BEFORE staging so their ~900-cyc HBM latency
    // overlaps the table staging + barrier instead of following it.
    float4 w0 = *reinterpret_cast<const float4*>(wp + base);
    float4 w1 = *reinterpret_cast<const float4*>(wp + base + 4);

    const float* trow = tables + ((size_t)b * (FRAMES + 1) + (size_t)f0) * L;

    // Stage rows f0..f0+FPB (shared between adjacent frames), adding the wrap
    // column (c==L -> col 0) so fi==99 is handled exactly like the reference.
    for (int i = tid; i < ROWS * LSTR; i += 256) {
        int r = i / LSTR;               // magic-mul, no HW div
        int c = i - r * LSTR;
        tab[i] = trow[r * L + (c == L ? 0 : c)];
    }
    __syncthreads();

    const int r  = tid >> 5;            // frame within block (0..7)
    const int h0 = (tid & 31) * 8;      // hop position of this thread's first elem
    const float* __restrict__ row = tab + r * LSTR;

    float wv[8] = {w0.x, w0.y, w0.z, w0.w, w1.x, w1.y, w1.z, w1.w};
    float res[8];
#pragma unroll
    for (int j = 0; j < 8; ++j) {
        float idx_raw = wv[j] * (float)L;
        int fi = (int)idx_raw;                        // trunc; wp >= 0
        fi = fi < 0 ? 0 : (fi > L - 1 ? L - 1 : fi);  // clip like reference
        float p  = idx_raw - (float)fi;
        float a0 = row[fi];            // floor_flow[fi]     } ds_read2_b32
        float a1 = row[fi + 1];        // floor_flow[fi+1]   }
        float c0 = row[fi + LSTR];     // ceil_flow[fi]      } ds_read2_b32
        float c1 = row[fi + LSTR + 1]; // ceil_flow[fi+1]    }
        float sf = fmaf(a1 - a0, p, a0);
        float sc = fmaf(c1 - c0, p, c0);
        float p2 = (float)(h0 + j) * (1.0f / HOP);
        res[j] = fmaf(sc - sf, p2, sf);
    }

    *reinterpret_cast<float4*>(out + base)     = make_float4(res[0], res[1], res[2], res[3]);
    *reinterpret_cast<float4*>(out + base + 4) = make_float4(res[4], res[5], res[6], res[7]);
}

extern "C" void kernel_launch(void* const* d_in, const int* in_sizes, int n_in,
                              void* d_out, int out_size, void* d_ws, size_t ws_size,
                              hipStream_t stream) {
    const float* wp     = (const float*)d_in[0];
    const float* tables = (const float*)d_in[1];
    // d_in[2] is hop_length (scalar int) — baked in as constexpr HOP.
    float* out = (float*)d_out;

    dim3 grid(B * (FRAMES / FPB));   // 32 * 256 = 8192 blocks
    glottal_kernel<<<grid, 256, 0, stream>>>(wp, tables, out);
}

// Round 6
// 135.742 us; speedup vs baseline: 1.0155x; 1.0155x over previous
//
#include <hip/hip_runtime.h>

// Problem constants (from setup_inputs): B=32, S=524288, HOP=256, L=100.
constexpr int HOP    = 256;
constexpr int L      = 100;
constexpr int FRAMES = 2048;   // S / HOP
constexpr int B      = 32;
constexpr int FPB    = 8;      // frames per block (2 per wave, 4 waves)
constexpr int WSTR   = 101;    // LDS row stride (odd -> full bank spread; idx 100 = wrap col)
constexpr int WROWS  = 3;      // rows staged per wave (2 frames -> rows f..f+2)

// R5 -> R6: __syncthreads after staging forced a vmcnt(0)+lgkmcnt(0) drain of
// ALL waves' loads before ANY wave could gather -> phases ran serially
// (VALU 19% + LDS ~20% + HBM ~44% summed to the observed 41 us with nothing
// saturated). Now each WAVE stages only its own 3 table rows into a private
// LDS region and proceeds wave-synchronously: no block barrier, waves slide
// independently, memory/LDS/VALU phases of different waves overlap.
__global__ __launch_bounds__(256) void glottal_kernel(
    const float* __restrict__ wp,
    const float* __restrict__ tables,
    float* __restrict__ out)
{
    __shared__ float tab[4][WROWS * WSTR];   // 4 waves x 303 floats = 4848 B

    const int tid  = threadIdx.x;
    const int w    = tid >> 6;          // wave id 0..3
    const int lane = tid & 63;
    const int b    = blockIdx.x >> 8;   // / (FRAMES/FPB) = 256
    const int g    = blockIdx.x & 255;
    const int f0   = g * FPB + w * 2;   // this wave's first frame

    // Streaming wp load (coalesced float4 x2), issued first.
    const size_t base = ((size_t)b * FRAMES + (size_t)(g * FPB)) * HOP + (size_t)tid * 8;
    float4 w0 = *reinterpret_cast<const float4*>(wp + base);
    float4 w1 = *reinterpret_cast<const float4*>(wp + base + 4);

    // Stage this wave's rows f0..f0+2 (303 floats incl. per-row wrap col).
    const float* trow = tables + ((size_t)b * (FRAMES + 1) + (size_t)f0) * L;
    float* wtab = tab[w];
#pragma unroll
    for (int it = 0; it < 5; ++it) {
        int i = lane + it * 64;
        if (i < WROWS * WSTR) {
            int r = i / WSTR;                   // magic-mul
            int c = i - r * WSTR;
            wtab[i] = trow[r * L + (c == L ? 0 : c)];
        }
    }
    // Wave-synchronous fence: all this wave's ds_writes visible before reads.
    // (Lockstep wave64 => all lanes' writes are issued; waitcnt drains them.
    //  wave_barrier stops the compiler reordering LDS ops across the fence.)
    __builtin_amdgcn_wave_barrier();
    asm volatile("s_waitcnt lgkmcnt(0)" ::: "memory");
    __builtin_amdgcn_wave_barrier();

    const int rw = lane >> 5;               // frame within wave (0/1)
    const int h0 = (lane & 31) * 8;         // hop position of first elem
    const float* __restrict__ row = wtab + rw * WSTR;

    float wv[8] = {w0.x, w0.y, w0.z, w0.w, w1.x, w1.y, w1.z, w1.w};
    float res[8];
#pragma unroll
    for (int j = 0; j < 8; ++j) {
        float idx_raw = wv[j] * (float)L;
        int fi = (int)idx_raw;                        // trunc; wp >= 0
        fi = fi < 0 ? 0 : (fi > L - 1 ? L - 1 : fi);  // clip like reference
        float p  = idx_raw - (float)fi;
        float a0 = row[fi];            // floor_flow[fi]     } ds_read2_b32
        float a1 = row[fi + 1];        // floor_flow[fi+1]   }
        float c0 = row[fi + WSTR];     // ceil_flow[fi]      } ds_read2_b32
        float c1 = row[fi + WSTR + 1]; // ceil_flow[fi+1]    }
        float sf = fmaf(a1 - a0, p, a0);
        float sc = fmaf(c1 - c0, p, c0);
        float p2 = (float)(h0 + j) * (1.0f / HOP);
        res[j] = fmaf(sc - sf, p2, sf);
    }

    *reinterpret_cast<float4*>(out + base)     = make_float4(res[0], res[1], res[2], res[3]);
    *reinterpret_cast<float4*>(out + base + 4) = make_float4(res[4], res[5], res[6], res[7]);
}

extern "C" void kernel_launch(void* const* d_in, const int* in_sizes, int n_in,
                              void* d_out, int out_size, void* d_ws, size_t ws_size,
                              hipStream_t stream) {
    const float* wp     = (const float*)d_in[0];
    const float* tables = (const float*)d_in[1];
    // d_in[2] is hop_length (scalar int) — baked in as constexpr HOP.
    float* out = (float*)d_out;

    dim3 grid(B * (FRAMES / FPB));   // 32 * 256 = 8192 blocks
    glottal_kernel<<<grid, 256, 0, stream>>>(wp, tables, out);
}